// Round 1
// baseline (2339.026 us; speedup 1.0000x reference)
//
#include <hip/hip_runtime.h>
#include <math.h>

// Problem constants
// B=4 S=3 E=7 IMG=256 PH=8 H=32 D=128 NH=4 DK=64 DC=128 DH=32 TEMB=256 LK=128 GROUPS=16

// ---------------------------------------------------------------------------
// K1: patchify x (4,3,7,256,256) -> xp_pad (12, 448, 34, 34) with zero ring.
// channel c = p1*56 + p2*7 + e ; value = x[b,s,e, h1*8+p1, h2*8+p2]
// ---------------------------------------------------------------------------
__global__ void k_patchify(const float* __restrict__ x, float* __restrict__ xp_pad) {
    int idx = blockIdx.x * 256 + threadIdx.x;
    const int total = 12 * 448 * 34 * 34;
    if (idx >= total) return;
    int yx = idx % (34 * 34);
    int c  = (idx / (34 * 34)) % 448;
    int bs = idx / (448 * 34 * 34);
    int y = yx / 34, xc = yx % 34;
    float v = 0.0f;
    if (y >= 1 && y <= 32 && xc >= 1 && xc <= 32) {
        int h1 = y - 1, h2 = xc - 1;
        int p1 = c / 56, p2 = (c / 7) % 8, e = c % 7;
        v = x[(size_t)(bs * 7 + e) * 65536 + (size_t)(h1 * 8 + p1) * 256 + (h2 * 8 + p2)];
    }
    xp_pad[idx] = v;
}

// ---------------------------------------------------------------------------
// K2: weight repacks.
// pw9[tap][c][d]  (9,448,128) from patch_w (128,448,3,3)
// uw9[tap][ic][oc](9,128,448) from unpatch_w (448,128,3,3)
// qwT[dq][o]      (128,256)   from fc1q_w (256,128)
// ---------------------------------------------------------------------------
__global__ void k_repack(const float* __restrict__ patch_w, const float* __restrict__ unpatch_w,
                         const float* __restrict__ fc1q_w,
                         float* __restrict__ pw9, float* __restrict__ uw9, float* __restrict__ qwT) {
    int idx = blockIdx.x * 256 + threadIdx.x;
    if (idx < 516096) {
        int d = idx % 128; int c = (idx / 128) % 448; int tap = idx / (128 * 448);
        pw9[idx] = patch_w[((size_t)d * 448 + c) * 9 + tap];
        int oc = idx % 448; int ic = (idx / 448) % 128; int tap2 = idx / (448 * 128);
        uw9[idx] = unpatch_w[((size_t)oc * 128 + ic) * 9 + tap2];
    }
    if (idx < 32768) {
        int o = idx % 256, dq = idx / 256;
        qwT[idx] = fc1q_w[o * 128 + dq];
    }
}

// ---------------------------------------------------------------------------
// K3: init xp2 (12,128,32,32) = patch_b[d] + pos_embed[d,hw]  (conv1 atomics add onto this)
// ---------------------------------------------------------------------------
__global__ void k_init_xp2(const float* __restrict__ patch_b, const float* __restrict__ pos,
                           float* __restrict__ xp2) {
    int idx = blockIdx.x * 256 + threadIdx.x;   // 1572864 total, grid exact
    int hw = idx & 1023; int d = (idx >> 10) & 127;
    xp2[idx] = patch_b[d] + pos[d * 1024 + hw];
}

// ---------------------------------------------------------------------------
// K4: conv1 3x3 pad1 : xp_pad (bs,448,34,34) * pw9 -> += xp2 (bs,128,32,32)
// grid (8 htiles, 12 bs, 12 = 3 tap-groups x 4 channel-quarters); block 256
// tile 128 spatial x 128 d; thread 8x8. K-split raises grid 288 -> 1152 blocks
// (was 1.1 blocks/CU -> Occupancy 10.5%, VALUBusy 22%; atomics are cheap at 6% HBM).
// ---------------------------------------------------------------------------
__global__ __launch_bounds__(256) void k_conv1(const float* __restrict__ xp_pad,
                                               const float* __restrict__ pw9,
                                               float* __restrict__ xp2) {
    int htile = blockIdx.x, bs = blockIdx.y, z = blockIdx.z;
    int tg = z >> 2, cq = z & 3;         // tap-group 0..2, channel-quarter 0..3
    int h0 = htile * 4;
    int tid = threadIdx.x;
    int sp0 = (tid & 15) * 8;    // 0..120 (spatial within 128-tile)
    int d0  = (tid >> 4) * 8;    // 0..120
    __shared__ __align__(16) float As[8][4][36];   // [k][row][col] (pad 36 breaks 4-way conflicts)
    __shared__ __align__(16) float Ws[8][128];
    float acc[8][8];
#pragma unroll
    for (int i = 0; i < 8; ++i)
#pragma unroll
        for (int j = 0; j < 8; ++j) acc[i][j] = 0.0f;

    const float* inb = xp_pad + (size_t)bs * 448 * 1156;
    for (int tap = tg * 3; tap < tg * 3 + 3; ++tap) {
        int kh = tap / 3, kw = tap % 3;
        for (int c0 = cq * 112; c0 < cq * 112 + 112; c0 += 8) {
#pragma unroll
            for (int t = 0; t < 4; ++t) {             // stage A: 8k x 128sp
                int j = tid + t * 256;
                int k = j >> 7, sp = j & 127;
                int r = sp >> 5, wv = sp & 31;
                As[k][r][wv] = inb[(size_t)(c0 + k) * 1156 + (h0 + r + kh) * 34 + (wv + kw)];
            }
            const float* wb = pw9 + ((size_t)tap * 448 + c0) * 128;
#pragma unroll
            for (int t = 0; t < 4; ++t) {             // stage W: contiguous 1024 floats
                int j = tid + t * 256;
                Ws[j >> 7][j & 127] = wb[j];
            }
            __syncthreads();
            int r = sp0 >> 5, cc = sp0 & 31;
#pragma unroll
            for (int k = 0; k < 8; ++k) {
                float4 a0 = *(const float4*)&As[k][r][cc];
                float4 a1 = *(const float4*)&As[k][r][cc + 4];
                float4 w0 = *(const float4*)&Ws[k][d0];
                float4 w1 = *(const float4*)&Ws[k][d0 + 4];
                float av[8] = {a0.x, a0.y, a0.z, a0.w, a1.x, a1.y, a1.z, a1.w};
                float wv[8] = {w0.x, w0.y, w0.z, w0.w, w1.x, w1.y, w1.z, w1.w};
#pragma unroll
                for (int i = 0; i < 8; ++i)
#pragma unroll
                    for (int j = 0; j < 8; ++j) acc[i][j] += av[i] * wv[j];
            }
            __syncthreads();
        }
    }
    size_t base = (size_t)bs * 131072 + (size_t)h0 * 32;
#pragma unroll
    for (int j = 0; j < 8; ++j)
#pragma unroll
        for (int i = 0; i < 8; ++i)
            atomicAdd(&xp2[base + (size_t)(d0 + j) * 1024 + sp0 + i], acc[i][j]);
}

// ---------------------------------------------------------------------------
// K5: group stats: 64 blocks, one per (b,g): 24576 contiguous floats of xp2
// ---------------------------------------------------------------------------
__global__ void k_gstats(const float* __restrict__ xp2, float* __restrict__ gstat) {
    int bg = blockIdx.x;
    const float* p = xp2 + (size_t)bg * 24576;
    float s = 0.0f, s2 = 0.0f;
    for (int i = threadIdx.x; i < 24576; i += 256) { float v = p[i]; s += v; s2 += v * v; }
#pragma unroll
    for (int off = 32; off; off >>= 1) { s += __shfl_down(s, off); s2 += __shfl_down(s2, off); }
    __shared__ float ws[4], ws2[4];
    int w = threadIdx.x >> 6, lane = threadIdx.x & 63;
    if (lane == 0) { ws[w] = s; ws2[w] = s2; }
    __syncthreads();
    if (threadIdx.x == 0) {
        float S = ws[0] + ws[1] + ws[2] + ws[3];
        float S2 = ws2[0] + ws2[1] + ws2[2] + ws2[3];
        float mu = S * (1.0f / 24576.0f);
        float var = S2 * (1.0f / 24576.0f) - mu * mu;
        gstat[bg * 2] = mu;
        gstat[bg * 2 + 1] = rsqrtf(var + 1e-5f);
    }
}

// ---------------------------------------------------------------------------
// K6: qred[n,dq] = sum_s w2[s]*groupnorm(xp2)[flat n*384+dq*3+s]
// flat-within-b index f: group g = f/24576, gamma idx gi = f/3072
// ---------------------------------------------------------------------------
__global__ void k_qred(const float* __restrict__ xp2, const float* __restrict__ gstat,
                       const float* __restrict__ gamma, const float* __restrict__ beta,
                       const float* __restrict__ w2, float* __restrict__ qred) {
    int idx = blockIdx.x * 256 + threadIdx.x;   // n*128+dq, total 524288
    int dq = idx & 127, n = idx >> 7;
    int b = n >> 10;
    int f = (n & 1023) * 384 + dq * 3;
    const float* src = xp2 + (size_t)b * 393216 + f;
    float out = 0.0f;
#pragma unroll
    for (int s = 0; s < 3; ++s) {
        int ff = f + s;
        int g = ff / 24576;
        int gi = ff / 3072;
        float mu = gstat[(b * 16 + g) * 2], rstd = gstat[(b * 16 + g) * 2 + 1];
        float v = (src[s] - mu) * rstd * gamma[gi] + beta[gi];
        out += w2[s] * v;
    }
    qred[idx] = out;
}

// ---------------------------------------------------------------------------
// K7: q[n,o] = qwT[:,o] . qred[n,:] + fc1q_b[o]*sum(w2) + fc2q_b
// grid 1024 blocks: 4 n-rows each; thread = o
// ---------------------------------------------------------------------------
__global__ void k_qgemm(const float* __restrict__ qred, const float* __restrict__ qwT,
                        const float* __restrict__ fc1q_b, const float* __restrict__ w2,
                        const float* __restrict__ fc2q_b, float* __restrict__ q) {
    int o = threadIdx.x;
    int n0 = blockIdx.x * 4;
    __shared__ float sq[4][128];
    for (int t = threadIdx.x; t < 512; t += 256) sq[t >> 7][t & 127] = qred[n0 * 128 + t];
    __syncthreads();
    float a0 = 0, a1 = 0, a2 = 0, a3 = 0;
    for (int k = 0; k < 128; ++k) {
        float wv = qwT[k * 256 + o];
        a0 += wv * sq[0][k]; a1 += wv * sq[1][k]; a2 += wv * sq[2][k]; a3 += wv * sq[3][k];
    }
    float bias = fc1q_b[o] * (w2[0] + w2[1] + w2[2]) + fc2q_b[0];
    q[(size_t)(n0 + 0) * 256 + o] = a0 + bias;
    q[(size_t)(n0 + 1) * 256 + o] = a1 + bias;
    q[(size_t)(n0 + 2) * 256 + o] = a2 + bias;
    q[(size_t)(n0 + 3) * 256 + o] = a3 + bias;
}

// ---------------------------------------------------------------------------
// K8: attention, one wave per row r (16384 rows). LK=128, DK=64, DH=32.
// writes o2[(r%4096)*128 + (r>>12)*32 + c]  (the mis-reshape in the reference)
// ---------------------------------------------------------------------------
__global__ __launch_bounds__(256) void k_attn(const float* __restrict__ q,
                                              const float* __restrict__ kc,
                                              const float* __restrict__ vc,
                                              float* __restrict__ o2) {
    int w = threadIdx.x >> 6, lane = threadIdx.x & 63;
    int r = blockIdx.x * 4 + w;
    int n = r >> 2, nh = r & 3;
    __shared__ float sQ[4][64];
    __shared__ float sP[4][128];
    sQ[w][lane] = q[(size_t)n * 256 + nh * 64 + lane];
    __syncthreads();
    const float4* K4 = (const float4*)(kc + (size_t)r * 8192);
    const float4* q4 = (const float4*)sQ[w];
    float s0 = 0.0f, s1 = 0.0f;
#pragma unroll
    for (int i = 0; i < 16; ++i) {
        float4 qv = q4[i];
        float4 k0 = K4[lane * 16 + i];
        float4 k1 = K4[(64 + lane) * 16 + i];
        s0 += qv.x * k0.x + qv.y * k0.y + qv.z * k0.z + qv.w * k0.w;
        s1 += qv.x * k1.x + qv.y * k1.y + qv.z * k1.z + qv.w * k1.w;
    }
    s0 *= 0.125f; s1 *= 0.125f;
    float mx = fmaxf(s0, s1);
#pragma unroll
    for (int off = 32; off; off >>= 1) mx = fmaxf(mx, __shfl_xor(mx, off));
    float p0 = __expf(s0 - mx), p1 = __expf(s1 - mx);
    float sum = p0 + p1;
#pragma unroll
    for (int off = 32; off; off >>= 1) sum += __shfl_xor(sum, off);
    float inv = 1.0f / sum;
    sP[w][lane] = p0 * inv;
    sP[w][64 + lane] = p1 * inv;
    __syncthreads();
    const float* V = vc + (size_t)r * 4096;
    int c = lane & 31, half = lane >> 5;
    float acc = 0.0f;
#pragma unroll 8
    for (int l = 0; l < 64; ++l) {
        int ll = half * 64 + l;
        acc += sP[w][ll] * V[ll * 32 + c];
    }
    acc += __shfl_down(acc, 32);
    if (lane < 32) {
        int m = r & 4095, a = r >> 12;
        o2[(size_t)m * 128 + a * 32 + lane] = acc;
    }
}

// ---------------------------------------------------------------------------
// K9: outproj: op_pad interior (b,o,1+h,1+w) = sum_c W[o,c]*o2[b*131072+c*1024+hw] + b[o]
// grid (4 hw-chunks, 128 o, 4 b)
// ---------------------------------------------------------------------------
__global__ void k_outproj(const float* __restrict__ o2, const float* __restrict__ opw,
                          const float* __restrict__ opb, float* __restrict__ op_pad) {
    int hw = blockIdx.x * 256 + threadIdx.x;
    int o = blockIdx.y, b = blockIdx.z;
    const float* src = o2 + (size_t)b * 131072 + hw;
    const float* wrow = opw + o * 128;
    float acc = opb[o];
#pragma unroll 4
    for (int cc = 0; cc < 128; ++cc) acc += wrow[cc] * src[(size_t)cc * 1024];
    int h = hw >> 5, wv = hw & 31;
    op_pad[((size_t)(b * 128 + o) * 34 + 1 + h) * 34 + 1 + wv] = acc;
}

// ---------------------------------------------------------------------------
// K10a: init u (4,7,256,256) with unpatch bias (conv2 atomics add onto this).
// u[(b*7+e)*65536 + H*256 + W] gets bias[oc], oc = (H&7)*56 + (W&7)*7 + e
// ---------------------------------------------------------------------------
__global__ void k_init_u(const float* __restrict__ upb, float* __restrict__ u) {
    int idx = blockIdx.x * 256 + threadIdx.x;   // 1835008 total, grid exact (7168 blocks)
    int W = idx & 255, H = (idx >> 8) & 255;
    int e = (idx >> 16) % 7;
    u[idx] = upb[(H & 7) * 56 + (W & 7) * 7 + e];
}

// ---------------------------------------------------------------------------
// K10: conv2 3x3 pad1 (4,128,34,34)->(4,448,32,32), atomic-scattered to u (4,7,256,256)
// grid (8 htiles, 4 b, 42 = 7 oc-tiles x 3 tap-groups x 2 channel-halves); block 256
// tile 128 spatial x 64 oc; thread 8x4. K-split raises grid 224 -> 1344 blocks.
// ---------------------------------------------------------------------------
__global__ __launch_bounds__(256) void k_conv2(const float* __restrict__ op_pad,
                                               const float* __restrict__ uw9,
                                               float* __restrict__ u) {
    int htile = blockIdx.x, b = blockIdx.y, z = blockIdx.z;
    int nt = z / 6, rem = z % 6, tg = rem >> 1, ch = rem & 1;
    int h0 = htile * 4;
    int tid = threadIdx.x;
    int sp0 = (tid & 15) * 8;
    int d0 = (tid >> 4) * 4;   // 0..60
    __shared__ __align__(16) float As[8][4][36];
    __shared__ __align__(16) float Ws[8][64];
    float acc[8][4];
#pragma unroll
    for (int j = 0; j < 4; ++j)
#pragma unroll
        for (int i = 0; i < 8; ++i) acc[i][j] = 0.0f;

    const float* inb = op_pad + (size_t)b * 128 * 1156;
    for (int tap = tg * 3; tap < tg * 3 + 3; ++tap) {
        int kh = tap / 3, kw = tap % 3;
        for (int c0 = ch * 64; c0 < ch * 64 + 64; c0 += 8) {
#pragma unroll
            for (int t = 0; t < 4; ++t) {
                int j = tid + t * 256;
                int k = j >> 7, sp = j & 127;
                int rr = sp >> 5, wv = sp & 31;
                As[k][rr][wv] = inb[(size_t)(c0 + k) * 1156 + (h0 + rr + kh) * 34 + (wv + kw)];
            }
#pragma unroll
            for (int t = 0; t < 2; ++t) {
                int jj = tid + t * 256;
                int k = jj >> 6, oc = jj & 63;
                Ws[k][oc] = uw9[((size_t)tap * 128 + c0 + k) * 448 + nt * 64 + oc];
            }
            __syncthreads();
            int rr = sp0 >> 5, cc = sp0 & 31;
#pragma unroll
            for (int k = 0; k < 8; ++k) {
                float4 a0 = *(const float4*)&As[k][rr][cc];
                float4 a1 = *(const float4*)&As[k][rr][cc + 4];
                float4 w0 = *(const float4*)&Ws[k][d0];
                float av[8] = {a0.x, a0.y, a0.z, a0.w, a1.x, a1.y, a1.z, a1.w};
                float wv4[4] = {w0.x, w0.y, w0.z, w0.w};
#pragma unroll
                for (int i = 0; i < 8; ++i)
#pragma unroll
                    for (int j = 0; j < 4; ++j) acc[i][j] += av[i] * wv4[j];
            }
            __syncthreads();
        }
    }
#pragma unroll
    for (int j = 0; j < 4; ++j) {
        int oc = nt * 64 + d0 + j;
        int e = oc % 7, p2 = (oc / 7) & 7, p1 = oc / 56;
#pragma unroll
        for (int i = 0; i < 8; ++i) {
            int sp = sp0 + i;
            int hh = h0 + (sp >> 5), ww = sp & 31;
            atomicAdd(&u[((size_t)(b * 7 + e) * 256 + hh * 8 + p1) * 256 + ww * 8 + p2], acc[i][j]);
        }
    }
}

// ---------------------------------------------------------------------------
// K11: layernorm partial sums over u per b (458752 elems): 256 blocks -> atomics
// ---------------------------------------------------------------------------
__global__ void k_lnpart(const float* __restrict__ u, float* __restrict__ acc2) {
    int b = blockIdx.x >> 6, blk = blockIdx.x & 63;
    const float* p = u + (size_t)b * 458752 + (size_t)blk * 7168;
    float s = 0.0f, s2 = 0.0f;
    for (int i = threadIdx.x; i < 7168; i += 256) { float v = p[i]; s += v; s2 += v * v; }
#pragma unroll
    for (int off = 32; off; off >>= 1) { s += __shfl_down(s, off); s2 += __shfl_down(s2, off); }
    __shared__ float ws[4], ws2[4];
    int w = threadIdx.x >> 6, lane = threadIdx.x & 63;
    if (lane == 0) { ws[w] = s; ws2[w] = s2; }
    __syncthreads();
    if (threadIdx.x == 0) {
        atomicAdd(&acc2[b * 2], ws[0] + ws[1] + ws[2] + ws[3]);
        atomicAdd(&acc2[b * 2 + 1], ws2[0] + ws2[1] + ws2[2] + ws2[3]);
    }
}

// ---------------------------------------------------------------------------
// K12: finalize stats + modulation c = silu(emb) @ mod_w.T + mod_b
// mstat[b*16 + 0..13] = c; [14]=mu2; [15]=rstd2
// ---------------------------------------------------------------------------
__global__ void k_finalize(const float* __restrict__ acc2, const float* __restrict__ emb,
                           const float* __restrict__ mod_w, const float* __restrict__ mod_b,
                           float* __restrict__ mstat) {
    int b = blockIdx.x;
    __shared__ float se[256];
    float ev = emb[b * 256 + threadIdx.x];
    se[threadIdx.x] = ev / (1.0f + __expf(-ev));
    __syncthreads();
    if (threadIdx.x < 14) {
        float a = mod_b[threadIdx.x];
        const float* wr = mod_w + threadIdx.x * 256;
        for (int t = 0; t < 256; ++t) a += wr[t] * se[t];
        mstat[b * 16 + threadIdx.x] = a;
    } else if (threadIdx.x == 14) {
        mstat[b * 16 + 14] = acc2[b * 2] * (1.0f / 458752.0f);
    } else if (threadIdx.x == 15) {
        float mu = acc2[b * 2] * (1.0f / 458752.0f);
        float var = acc2[b * 2 + 1] * (1.0f / 458752.0f) - mu * mu;
        mstat[b * 16 + 15] = rsqrtf(var + 1e-5f);
    }
}

// ---------------------------------------------------------------------------
// K13: final elementwise: layernorm-mod, enlarge, gated gelu, ff2, +skip
// ---------------------------------------------------------------------------
__global__ void k_final(const float* __restrict__ u, const float* __restrict__ mstat,
                        const float* __restrict__ ew, const float* __restrict__ eb,
                        const float* __restrict__ f2w, const float* __restrict__ f2b,
                        float* __restrict__ out) {
    int pix = blockIdx.x * 256 + threadIdx.x;   // 262144 total
    int b = pix >> 16, p = pix & 65535;
    const float* ub = u + (size_t)b * 458752 + p;
    float mu = mstat[b * 16 + 14], rstd = mstat[b * 16 + 15];
    float un[7], skip[7];
#pragma unroll
    for (int e = 0; e < 7; ++e) {
        float v = ub[(size_t)e * 65536];
        skip[e] = v;
        float nv = (v - mu) * rstd;
        un[e] = nv * (1.0f + mstat[b * 16 + e]) + mstat[b * 16 + 7 + e];
    }
    float hf[7];
#pragma unroll
    for (int e = 0; e < 7; ++e) {
        float x1 = eb[e], x2 = eb[7 + e];
#pragma unroll
        for (int cc = 0; cc < 7; ++cc) {
            x1 += ew[e * 7 + cc] * un[cc];
            x2 += ew[(7 + e) * 7 + cc] * un[cc];
        }
        float g2 = 0.5f * x2 * (1.0f + erff(x2 * 0.70710678118f));
        float gu = 0.5f * un[e] * (1.0f + erff(un[e] * 0.70710678118f));
        hf[e] = gu + x1 * g2;
    }
#pragma unroll
    for (int o = 0; o < 7; ++o) {
        float a = f2b[o];
#pragma unroll
        for (int cc = 0; cc < 7; ++cc) a += f2w[o * 7 + cc] * hf[cc];
        out[(size_t)b * 458752 + (size_t)o * 65536 + p] = a + skip[o];
    }
}

// ---------------------------------------------------------------------------
extern "C" void kernel_launch(void* const* d_in, const int* in_sizes, int n_in,
                              void* d_out, int out_size, void* d_ws, size_t ws_size,
                              hipStream_t stream) {
    const float* x         = (const float*)d_in[0];
    const float* k_cond    = (const float*)d_in[1];
    const float* v_cond    = (const float*)d_in[2];
    const float* emb       = (const float*)d_in[3];
    const float* pos_embed = (const float*)d_in[4];
    const float* patch_w   = (const float*)d_in[5];
    const float* patch_b   = (const float*)d_in[6];
    const float* gn_gamma  = (const float*)d_in[7];
    const float* gn_beta   = (const float*)d_in[8];
    const float* fc1q_w    = (const float*)d_in[9];
    const float* fc1q_b    = (const float*)d_in[10];
    const float* fc2q_w    = (const float*)d_in[11];
    const float* fc2q_b    = (const float*)d_in[12];
    const float* outproj_w = (const float*)d_in[13];
    const float* outproj_b = (const float*)d_in[14];
    const float* unpatch_w = (const float*)d_in[15];
    const float* unpatch_b = (const float*)d_in[16];
    const float* mod_w     = (const float*)d_in[17];
    const float* mod_b     = (const float*)d_in[18];
    const float* enlarge_w = (const float*)d_in[19];
    const float* enlarge_b = (const float*)d_in[20];
    const float* ff2_w     = (const float*)d_in[21];
    const float* ff2_b     = (const float*)d_in[22];
    float* out = (float*)d_out;

    float* ws = (float*)d_ws;
    size_t off = 0;
    auto alloc = [&](size_t n) { float* p = ws + off; off += n; return p; };
    float* xp_pad = alloc(12ull * 448 * 1156);   // 6,214,656
    float* pw9    = alloc(516096);
    float* uw9    = alloc(516096);
    float* qwT    = alloc(32768);
    float* xp2    = alloc(1572864);
    float* gstat  = alloc(128);
    float* qred   = alloc(524288);
    float* qbuf   = alloc(1048576);
    float* o2     = alloc(524288);
    float* op_pad = alloc(4ull * 128 * 1156);    // 591,872
    float* ubuf   = alloc(1835008);
    float* acc2   = alloc(8);
    float* mstat  = alloc(64);

    hipMemsetAsync(acc2, 0, 8 * sizeof(float), stream);
    hipMemsetAsync(op_pad, 0, 4ull * 128 * 1156 * sizeof(float), stream);

    k_patchify<<<(12 * 448 * 1156 + 255) / 256, 256, 0, stream>>>(x, xp_pad);
    k_repack<<<2016, 256, 0, stream>>>(patch_w, unpatch_w, fc1q_w, pw9, uw9, qwT);
    k_init_xp2<<<6144, 256, 0, stream>>>(patch_b, pos_embed, xp2);
    k_init_u<<<7168, 256, 0, stream>>>(unpatch_b, ubuf);
    k_conv1<<<dim3(8, 12, 12), 256, 0, stream>>>(xp_pad, pw9, xp2);
    k_gstats<<<64, 256, 0, stream>>>(xp2, gstat);
    k_qred<<<2048, 256, 0, stream>>>(xp2, gstat, gn_gamma, gn_beta, fc2q_w, qred);
    k_qgemm<<<1024, 256, 0, stream>>>(qred, qwT, fc1q_b, fc2q_w, fc2q_b, qbuf);
    k_attn<<<4096, 256, 0, stream>>>(qbuf, k_cond, v_cond, o2);
    k_outproj<<<dim3(4, 128, 4), 256, 0, stream>>>(o2, outproj_w, outproj_b, op_pad);
    k_conv2<<<dim3(8, 4, 42), 256, 0, stream>>>(op_pad, uw9, ubuf);
    k_lnpart<<<256, 256, 0, stream>>>(ubuf, acc2);
    k_finalize<<<4, 256, 0, stream>>>(acc2, emb, mod_w, mod_b, mstat);
    k_final<<<1024, 256, 0, stream>>>(ubuf, mstat, enlarge_w, enlarge_b, ff2_w, ff2_b, out);
}

// Round 2
// 1373.899 us; speedup vs baseline: 1.7025x; 1.7025x over previous
//
#include <hip/hip_runtime.h>
#include <math.h>

// Problem constants
// B=4 S=3 E=7 IMG=256 PH=8 H=32 D=128 NH=4 DK=64 DC=128 DH=32 TEMB=256 LK=128 GROUPS=16

// ---------------------------------------------------------------------------
// K1: patchify x (4,3,7,256,256) -> xp_pad (12, 448, 34, 34) with zero ring.
// channel c = p1*56 + p2*7 + e ; value = x[b,s,e, h1*8+p1, h2*8+p2]
// ---------------------------------------------------------------------------
__global__ void k_patchify(const float* __restrict__ x, float* __restrict__ xp_pad) {
    int idx = blockIdx.x * 256 + threadIdx.x;
    const int total = 12 * 448 * 34 * 34;
    if (idx >= total) return;
    int yx = idx % (34 * 34);
    int c  = (idx / (34 * 34)) % 448;
    int bs = idx / (448 * 34 * 34);
    int y = yx / 34, xc = yx % 34;
    float v = 0.0f;
    if (y >= 1 && y <= 32 && xc >= 1 && xc <= 32) {
        int h1 = y - 1, h2 = xc - 1;
        int p1 = c / 56, p2 = (c / 7) % 8, e = c % 7;
        v = x[(size_t)(bs * 7 + e) * 65536 + (size_t)(h1 * 8 + p1) * 256 + (h2 * 8 + p2)];
    }
    xp_pad[idx] = v;
}

// ---------------------------------------------------------------------------
// K2: weight repacks.
// pw9[tap][c][d]  (9,448,128) from patch_w (128,448,3,3)
// uw9[tap][ic][oc](9,128,448) from unpatch_w (448,128,3,3)
// qwT[dq][o]      (128,256)   from fc1q_w (256,128)
// ---------------------------------------------------------------------------
__global__ void k_repack(const float* __restrict__ patch_w, const float* __restrict__ unpatch_w,
                         const float* __restrict__ fc1q_w,
                         float* __restrict__ pw9, float* __restrict__ uw9, float* __restrict__ qwT) {
    int idx = blockIdx.x * 256 + threadIdx.x;
    if (idx < 516096) {
        int d = idx % 128; int c = (idx / 128) % 448; int tap = idx / (128 * 448);
        pw9[idx] = patch_w[((size_t)d * 448 + c) * 9 + tap];
        int oc = idx % 448; int ic = (idx / 448) % 128; int tap2 = idx / (448 * 128);
        uw9[idx] = unpatch_w[((size_t)oc * 128 + ic) * 9 + tap2];
    }
    if (idx < 32768) {
        int o = idx % 256, dq = idx / 256;
        qwT[idx] = fc1q_w[o * 128 + dq];
    }
}

// ---------------------------------------------------------------------------
// K4: conv1 3x3 pad1 : xp_pad (bs,448,34,34) * pw9 -> part1 (4 private K-partials).
// grid (16 sp-tiles of 64, 12 bs, 4 c-quarters of 112); block 256.
// Tile 64sp x 128d, thread 4sp x 8d. NO atomics: each block owns a private
// partial slice, coalesced float4 stores; k_red1 sums the 4 copies.
// (round-1 lesson: 12-way shared-output atomics -> 590 MB WRITE_SIZE, VALU 14%.)
// ---------------------------------------------------------------------------
__global__ __launch_bounds__(256) void k_conv1(const float* __restrict__ xp_pad,
                                               const float* __restrict__ pw9,
                                               float* __restrict__ part1) {
    int stile = blockIdx.x, bs = blockIdx.y, cq = blockIdx.z;
    int h0 = stile * 2;                  // 2 output rows per tile
    int tid = threadIdx.x;
    int sp0 = (tid & 15) * 4;            // 0..60 within 64-sp tile
    int d0  = (tid >> 4) * 8;            // 0..120
    __shared__ __align__(16) float As[16][2][36];   // 16 c x 2 rows x 32(+4 pad)
    __shared__ __align__(16) float Ws[16][128];
    float acc[4][8];                     // [sp][d]
#pragma unroll
    for (int i = 0; i < 4; ++i)
#pragma unroll
        for (int j = 0; j < 8; ++j) acc[i][j] = 0.0f;

    const float* inb = xp_pad + (size_t)bs * 448 * 1156;
    for (int tap = 0; tap < 9; ++tap) {
        int kh = tap / 3, kw = tap % 3;
        for (int c0 = cq * 112; c0 < cq * 112 + 112; c0 += 16) {
#pragma unroll
            for (int t = 0; t < 4; ++t) {            // stage A: 16c x 64sp = 1024
                int j = tid + t * 256;
                int k = j >> 6, sp = j & 63;
                int r = sp >> 5, wv = sp & 31;
                As[k][r][wv] = inb[(size_t)(c0 + k) * 1156 + (h0 + r + kh) * 34 + (wv + kw)];
            }
            const float* wb = pw9 + ((size_t)tap * 448 + c0) * 128;
#pragma unroll
            for (int t = 0; t < 8; ++t) {            // stage W: 16c x 128d = 2048
                int j = tid + t * 256;
                Ws[j >> 7][j & 127] = wb[j];
            }
            __syncthreads();
            int r = sp0 >> 5, cc = sp0 & 31;
#pragma unroll
            for (int k = 0; k < 16; ++k) {
                float4 a  = *(const float4*)&As[k][r][cc];
                float4 w0 = *(const float4*)&Ws[k][d0];
                float4 w1 = *(const float4*)&Ws[k][d0 + 4];
                float av[4] = {a.x, a.y, a.z, a.w};
                float wv[8] = {w0.x, w0.y, w0.z, w0.w, w1.x, w1.y, w1.z, w1.w};
#pragma unroll
                for (int i = 0; i < 4; ++i)
#pragma unroll
                    for (int j = 0; j < 8; ++j) acc[i][j] += av[i] * wv[j];
            }
            __syncthreads();
        }
    }
    // private partial: part1[cq*1572864 + (bs*128+d)*1024 + stile*64 + sp]
    float* dst = part1 + (size_t)(cq * 12 + bs) * 131072 + stile * 64;
#pragma unroll
    for (int j = 0; j < 8; ++j) {
        float4 v = make_float4(acc[0][j], acc[1][j], acc[2][j], acc[3][j]);
        *(float4*)&dst[(size_t)(d0 + j) * 1024 + sp0] = v;
    }
}

// ---------------------------------------------------------------------------
// K4b: reduce 4 conv1 partials + patch bias + pos_embed -> xp2 (12,128,32,32)
// ---------------------------------------------------------------------------
__global__ void k_red1(const float* __restrict__ part1, const float* __restrict__ patch_b,
                       const float* __restrict__ pos, float* __restrict__ xp2) {
    int idx = blockIdx.x * 256 + threadIdx.x;   // 1572864 total, grid exact
    int hw = idx & 1023; int d = (idx >> 10) & 127;
    float v = patch_b[d] + pos[d * 1024 + hw];
    v += part1[idx] + part1[idx + 1572864] + part1[idx + 2 * 1572864] + part1[idx + 3 * 1572864];
    xp2[idx] = v;
}

// ---------------------------------------------------------------------------
// K5: group stats: 64 blocks, one per (b,g): 24576 contiguous floats of xp2
// ---------------------------------------------------------------------------
__global__ void k_gstats(const float* __restrict__ xp2, float* __restrict__ gstat) {
    int bg = blockIdx.x;
    const float* p = xp2 + (size_t)bg * 24576;
    float s = 0.0f, s2 = 0.0f;
    for (int i = threadIdx.x; i < 24576; i += 256) { float v = p[i]; s += v; s2 += v * v; }
#pragma unroll
    for (int off = 32; off; off >>= 1) { s += __shfl_down(s, off); s2 += __shfl_down(s2, off); }
    __shared__ float ws[4], ws2[4];
    int w = threadIdx.x >> 6, lane = threadIdx.x & 63;
    if (lane == 0) { ws[w] = s; ws2[w] = s2; }
    __syncthreads();
    if (threadIdx.x == 0) {
        float S = ws[0] + ws[1] + ws[2] + ws[3];
        float S2 = ws2[0] + ws2[1] + ws2[2] + ws2[3];
        float mu = S * (1.0f / 24576.0f);
        float var = S2 * (1.0f / 24576.0f) - mu * mu;
        gstat[bg * 2] = mu;
        gstat[bg * 2 + 1] = rsqrtf(var + 1e-5f);
    }
}

// ---------------------------------------------------------------------------
// K6: qred[n,dq] = sum_s w2[s]*groupnorm(xp2)[flat n*384+dq*3+s]
// flat-within-b index f: group g = f/24576, gamma idx gi = f/3072
// ---------------------------------------------------------------------------
__global__ void k_qred(const float* __restrict__ xp2, const float* __restrict__ gstat,
                       const float* __restrict__ gamma, const float* __restrict__ beta,
                       const float* __restrict__ w2, float* __restrict__ qred) {
    int idx = blockIdx.x * 256 + threadIdx.x;   // n*128+dq, total 524288
    int dq = idx & 127, n = idx >> 7;
    int b = n >> 10;
    int f = (n & 1023) * 384 + dq * 3;
    const float* src = xp2 + (size_t)b * 393216 + f;
    float out = 0.0f;
#pragma unroll
    for (int s = 0; s < 3; ++s) {
        int ff = f + s;
        int g = ff / 24576;
        int gi = ff / 3072;
        float mu = gstat[(b * 16 + g) * 2], rstd = gstat[(b * 16 + g) * 2 + 1];
        float v = (src[s] - mu) * rstd * gamma[gi] + beta[gi];
        out += w2[s] * v;
    }
    qred[idx] = out;
}

// ---------------------------------------------------------------------------
// K7: q[n,o] = qwT[:,o] . qred[n,:] + fc1q_b[o]*sum(w2) + fc2q_b
// grid 1024 blocks: 4 n-rows each; thread = o
// ---------------------------------------------------------------------------
__global__ void k_qgemm(const float* __restrict__ qred, const float* __restrict__ qwT,
                        const float* __restrict__ fc1q_b, const float* __restrict__ w2,
                        const float* __restrict__ fc2q_b, float* __restrict__ q) {
    int o = threadIdx.x;
    int n0 = blockIdx.x * 4;
    __shared__ float sq[4][128];
    for (int t = threadIdx.x; t < 512; t += 256) sq[t >> 7][t & 127] = qred[n0 * 128 + t];
    __syncthreads();
    float a0 = 0, a1 = 0, a2 = 0, a3 = 0;
    for (int k = 0; k < 128; ++k) {
        float wv = qwT[k * 256 + o];
        a0 += wv * sq[0][k]; a1 += wv * sq[1][k]; a2 += wv * sq[2][k]; a3 += wv * sq[3][k];
    }
    float bias = fc1q_b[o] * (w2[0] + w2[1] + w2[2]) + fc2q_b[0];
    q[(size_t)(n0 + 0) * 256 + o] = a0 + bias;
    q[(size_t)(n0 + 1) * 256 + o] = a1 + bias;
    q[(size_t)(n0 + 2) * 256 + o] = a2 + bias;
    q[(size_t)(n0 + 3) * 256 + o] = a3 + bias;
}

// ---------------------------------------------------------------------------
// K8: attention, one wave per row r (16384 rows). LK=128, DK=64, DH=32.
// writes o2[(r%4096)*128 + (r>>12)*32 + c]  (the mis-reshape in the reference)
// ---------------------------------------------------------------------------
__global__ __launch_bounds__(256) void k_attn(const float* __restrict__ q,
                                              const float* __restrict__ kc,
                                              const float* __restrict__ vc,
                                              float* __restrict__ o2) {
    int w = threadIdx.x >> 6, lane = threadIdx.x & 63;
    int r = blockIdx.x * 4 + w;
    int n = r >> 2, nh = r & 3;
    __shared__ float sQ[4][64];
    __shared__ float sP[4][128];
    sQ[w][lane] = q[(size_t)n * 256 + nh * 64 + lane];
    __syncthreads();
    const float4* K4 = (const float4*)(kc + (size_t)r * 8192);
    const float4* q4 = (const float4*)sQ[w];
    float s0 = 0.0f, s1 = 0.0f;
#pragma unroll
    for (int i = 0; i < 16; ++i) {
        float4 qv = q4[i];
        float4 k0 = K4[lane * 16 + i];
        float4 k1 = K4[(64 + lane) * 16 + i];
        s0 += qv.x * k0.x + qv.y * k0.y + qv.z * k0.z + qv.w * k0.w;
        s1 += qv.x * k1.x + qv.y * k1.y + qv.z * k1.z + qv.w * k1.w;
    }
    s0 *= 0.125f; s1 *= 0.125f;
    float mx = fmaxf(s0, s1);
#pragma unroll
    for (int off = 32; off; off >>= 1) mx = fmaxf(mx, __shfl_xor(mx, off));
    float p0 = __expf(s0 - mx), p1 = __expf(s1 - mx);
    float sum = p0 + p1;
#pragma unroll
    for (int off = 32; off; off >>= 1) sum += __shfl_xor(sum, off);
    float inv = 1.0f / sum;
    sP[w][lane] = p0 * inv;
    sP[w][64 + lane] = p1 * inv;
    __syncthreads();
    const float* V = vc + (size_t)r * 4096;
    int c = lane & 31, half = lane >> 5;
    float acc = 0.0f;
#pragma unroll 8
    for (int l = 0; l < 64; ++l) {
        int ll = half * 64 + l;
        acc += sP[w][ll] * V[ll * 32 + c];
    }
    acc += __shfl_down(acc, 32);
    if (lane < 32) {
        int m = r & 4095, a = r >> 12;
        o2[(size_t)m * 128 + a * 32 + lane] = acc;
    }
}

// ---------------------------------------------------------------------------
// K9: outproj: op_pad interior (b,o,1+h,1+w) = sum_c W[o,c]*o2[b*131072+c*1024+hw] + b[o]
// grid (4 hw-chunks, 128 o, 4 b)
// ---------------------------------------------------------------------------
__global__ void k_outproj(const float* __restrict__ o2, const float* __restrict__ opw,
                          const float* __restrict__ opb, float* __restrict__ op_pad) {
    int hw = blockIdx.x * 256 + threadIdx.x;
    int o = blockIdx.y, b = blockIdx.z;
    const float* src = o2 + (size_t)b * 131072 + hw;
    const float* wrow = opw + o * 128;
    float acc = opb[o];
#pragma unroll 4
    for (int cc = 0; cc < 128; ++cc) acc += wrow[cc] * src[(size_t)cc * 1024];
    int h = hw >> 5, wv = hw & 31;
    op_pad[((size_t)(b * 128 + o) * 34 + 1 + h) * 34 + 1 + wv] = acc;
}

// ---------------------------------------------------------------------------
// K10: conv2 3x3 pad1 (4,128,34,34)->(4,448,32,32) + bias, scattered to u (4,7,256,256)
// grid (16 sp-tiles of 64, 4 b, 7 oc-tiles of 64); block 256; full-K, NO atomics.
// Tile 64sp x 64oc, thread 4sp x 4oc. Direct scatter stores (each address owned once).
// ---------------------------------------------------------------------------
__global__ __launch_bounds__(256) void k_conv2(const float* __restrict__ op_pad,
                                               const float* __restrict__ uw9,
                                               const float* __restrict__ upb,
                                               float* __restrict__ u) {
    int stile = blockIdx.x, b = blockIdx.y, nt = blockIdx.z;
    int h0 = stile * 2;
    int tid = threadIdx.x;
    int sp0 = (tid & 15) * 4;    // 0..60
    int oc0 = (tid >> 4) * 4;    // 0..60
    __shared__ __align__(16) float As[16][2][36];
    __shared__ __align__(16) float Ws[16][64];
    float acc[4][4];             // [sp][oc]
#pragma unroll
    for (int j = 0; j < 4; ++j) {
        float bias = upb[nt * 64 + oc0 + j];
#pragma unroll
        for (int i = 0; i < 4; ++i) acc[i][j] = bias;
    }
    const float* inb = op_pad + (size_t)b * 128 * 1156;
    for (int tap = 0; tap < 9; ++tap) {
        int kh = tap / 3, kw = tap % 3;
        for (int c0 = 0; c0 < 128; c0 += 16) {
#pragma unroll
            for (int t = 0; t < 4; ++t) {            // stage A: 16c x 64sp
                int j = tid + t * 256;
                int k = j >> 6, sp = j & 63;
                int r = sp >> 5, wv = sp & 31;
                As[k][r][wv] = inb[(size_t)(c0 + k) * 1156 + (h0 + r + kh) * 34 + (wv + kw)];
            }
#pragma unroll
            for (int t = 0; t < 4; ++t) {            // stage W: 16c x 64oc
                int j = tid + t * 256;
                int k = j >> 6, oc = j & 63;
                Ws[k][oc] = uw9[((size_t)tap * 128 + c0 + k) * 448 + nt * 64 + oc];
            }
            __syncthreads();
            int r = sp0 >> 5, cc = sp0 & 31;
#pragma unroll
            for (int k = 0; k < 16; ++k) {
                float4 a = *(const float4*)&As[k][r][cc];
                float4 w = *(const float4*)&Ws[k][oc0];
                float av[4] = {a.x, a.y, a.z, a.w};
                float wv4[4] = {w.x, w.y, w.z, w.w};
#pragma unroll
                for (int i = 0; i < 4; ++i)
#pragma unroll
                    for (int j = 0; j < 4; ++j) acc[i][j] += av[i] * wv4[j];
            }
            __syncthreads();
        }
    }
#pragma unroll
    for (int j = 0; j < 4; ++j) {
        int oc = nt * 64 + oc0 + j;
        int e = oc % 7, p2 = (oc / 7) & 7, p1 = oc / 56;
#pragma unroll
        for (int i = 0; i < 4; ++i) {
            int sp = sp0 + i;
            int hh = h0 + (sp >> 5), ww = sp & 31;
            u[((size_t)(b * 7 + e) * 256 + hh * 8 + p1) * 256 + ww * 8 + p2] = acc[i][j];
        }
    }
}

// ---------------------------------------------------------------------------
// K11: layernorm partial sums over u per b (458752 elems): 256 blocks -> atomics
// ---------------------------------------------------------------------------
__global__ void k_lnpart(const float* __restrict__ u, float* __restrict__ acc2) {
    int b = blockIdx.x >> 6, blk = blockIdx.x & 63;
    const float* p = u + (size_t)b * 458752 + (size_t)blk * 7168;
    float s = 0.0f, s2 = 0.0f;
    for (int i = threadIdx.x; i < 7168; i += 256) { float v = p[i]; s += v; s2 += v * v; }
#pragma unroll
    for (int off = 32; off; off >>= 1) { s += __shfl_down(s, off); s2 += __shfl_down(s2, off); }
    __shared__ float ws[4], ws2[4];
    int w = threadIdx.x >> 6, lane = threadIdx.x & 63;
    if (lane == 0) { ws[w] = s; ws2[w] = s2; }
    __syncthreads();
    if (threadIdx.x == 0) {
        atomicAdd(&acc2[b * 2], ws[0] + ws[1] + ws[2] + ws[3]);
        atomicAdd(&acc2[b * 2 + 1], ws2[0] + ws2[1] + ws2[2] + ws2[3]);
    }
}

// ---------------------------------------------------------------------------
// K12: finalize stats + modulation c = silu(emb) @ mod_w.T + mod_b
// mstat[b*16 + 0..13] = c; [14]=mu2; [15]=rstd2
// ---------------------------------------------------------------------------
__global__ void k_finalize(const float* __restrict__ acc2, const float* __restrict__ emb,
                           const float* __restrict__ mod_w, const float* __restrict__ mod_b,
                           float* __restrict__ mstat) {
    int b = blockIdx.x;
    __shared__ float se[256];
    float ev = emb[b * 256 + threadIdx.x];
    se[threadIdx.x] = ev / (1.0f + __expf(-ev));
    __syncthreads();
    if (threadIdx.x < 14) {
        float a = mod_b[threadIdx.x];
        const float* wr = mod_w + threadIdx.x * 256;
        for (int t = 0; t < 256; ++t) a += wr[t] * se[t];
        mstat[b * 16 + threadIdx.x] = a;
    } else if (threadIdx.x == 14) {
        mstat[b * 16 + 14] = acc2[b * 2] * (1.0f / 458752.0f);
    } else if (threadIdx.x == 15) {
        float mu = acc2[b * 2] * (1.0f / 458752.0f);
        float var = acc2[b * 2 + 1] * (1.0f / 458752.0f) - mu * mu;
        mstat[b * 16 + 15] = rsqrtf(var + 1e-5f);
    }
}

// ---------------------------------------------------------------------------
// K13: final elementwise: layernorm-mod, enlarge, gated gelu, ff2, +skip
// ---------------------------------------------------------------------------
__global__ void k_final(const float* __restrict__ u, const float* __restrict__ mstat,
                        const float* __restrict__ ew, const float* __restrict__ eb,
                        const float* __restrict__ f2w, const float* __restrict__ f2b,
                        float* __restrict__ out) {
    int pix = blockIdx.x * 256 + threadIdx.x;   // 262144 total
    int b = pix >> 16, p = pix & 65535;
    const float* ub = u + (size_t)b * 458752 + p;
    float mu = mstat[b * 16 + 14], rstd = mstat[b * 16 + 15];
    float un[7], skip[7];
#pragma unroll
    for (int e = 0; e < 7; ++e) {
        float v = ub[(size_t)e * 65536];
        skip[e] = v;
        float nv = (v - mu) * rstd;
        un[e] = nv * (1.0f + mstat[b * 16 + e]) + mstat[b * 16 + 7 + e];
    }
    float hf[7];
#pragma unroll
    for (int e = 0; e < 7; ++e) {
        float x1 = eb[e], x2 = eb[7 + e];
#pragma unroll
        for (int cc = 0; cc < 7; ++cc) {
            x1 += ew[e * 7 + cc] * un[cc];
            x2 += ew[(7 + e) * 7 + cc] * un[cc];
        }
        float g2 = 0.5f * x2 * (1.0f + erff(x2 * 0.70710678118f));
        float gu = 0.5f * un[e] * (1.0f + erff(un[e] * 0.70710678118f));
        hf[e] = gu + x1 * g2;
    }
#pragma unroll
    for (int o = 0; o < 7; ++o) {
        float a = f2b[o];
#pragma unroll
        for (int cc = 0; cc < 7; ++cc) a += f2w[o * 7 + cc] * hf[cc];
        out[(size_t)b * 458752 + (size_t)o * 65536 + p] = a + skip[o];
    }
}

// ---------------------------------------------------------------------------
extern "C" void kernel_launch(void* const* d_in, const int* in_sizes, int n_in,
                              void* d_out, int out_size, void* d_ws, size_t ws_size,
                              hipStream_t stream) {
    const float* x         = (const float*)d_in[0];
    const float* k_cond    = (const float*)d_in[1];
    const float* v_cond    = (const float*)d_in[2];
    const float* emb       = (const float*)d_in[3];
    const float* pos_embed = (const float*)d_in[4];
    const float* patch_w   = (const float*)d_in[5];
    const float* patch_b   = (const float*)d_in[6];
    const float* gn_gamma  = (const float*)d_in[7];
    const float* gn_beta   = (const float*)d_in[8];
    const float* fc1q_w    = (const float*)d_in[9];
    const float* fc1q_b    = (const float*)d_in[10];
    const float* fc2q_w    = (const float*)d_in[11];
    const float* fc2q_b    = (const float*)d_in[12];
    const float* outproj_w = (const float*)d_in[13];
    const float* outproj_b = (const float*)d_in[14];
    const float* unpatch_w = (const float*)d_in[15];
    const float* unpatch_b = (const float*)d_in[16];
    const float* mod_w     = (const float*)d_in[17];
    const float* mod_b     = (const float*)d_in[18];
    const float* enlarge_w = (const float*)d_in[19];
    const float* enlarge_b = (const float*)d_in[20];
    const float* ff2_w     = (const float*)d_in[21];
    const float* ff2_b     = (const float*)d_in[22];
    float* out = (float*)d_out;

    float* ws = (float*)d_ws;
    size_t off = 0;
    auto alloc = [&](size_t n) { float* p = ws + off; off += n; return p; };
    float* xp_pad = alloc(12ull * 448 * 1156);   // 6,214,656
    float* pw9    = alloc(516096);
    float* uw9    = alloc(516096);
    float* qwT    = alloc(32768);
    float* xp2    = alloc(1572864);
    float* gstat  = alloc(128);
    float* acc2   = alloc(8);
    float* mstat  = alloc(64);
    // shared region: part1 (4 x 1572864 = 6291456) is dead after k_red1;
    // the late-stage buffers alias it (qred written by k_qred, after red1).
    float* part1  = ws + off;
    float* qred   = part1;                       //   524288
    float* qbuf   = qred + 524288;               // 1,048,576
    float* o2     = qbuf + 1048576;              //   524288
    float* op_pad = o2 + 524288;                 //   591,872 (4*128*1156)
    float* ubuf   = op_pad + 591872;             // 1,835,008
    // region size = max(6291456, 4524544) = 6291456 floats

    hipMemsetAsync(acc2, 0, 8 * sizeof(float), stream);

    k_patchify<<<(12 * 448 * 1156 + 255) / 256, 256, 0, stream>>>(x, xp_pad);
    k_repack<<<2016, 256, 0, stream>>>(patch_w, unpatch_w, fc1q_w, pw9, uw9, qwT);
    k_conv1<<<dim3(16, 12, 4), 256, 0, stream>>>(xp_pad, pw9, part1);
    k_red1<<<6144, 256, 0, stream>>>(part1, patch_b, pos_embed, xp2);
    // op_pad aliases part1's region -> zero it only after red1 consumed part1
    hipMemsetAsync(op_pad, 0, 4ull * 128 * 1156 * sizeof(float), stream);
    k_gstats<<<64, 256, 0, stream>>>(xp2, gstat);
    k_qred<<<2048, 256, 0, stream>>>(xp2, gstat, gn_gamma, gn_beta, fc2q_w, qred);
    k_qgemm<<<1024, 256, 0, stream>>>(qred, qwT, fc1q_b, fc2q_w, fc2q_b, qbuf);
    k_attn<<<4096, 256, 0, stream>>>(qbuf, k_cond, v_cond, o2);
    k_outproj<<<dim3(4, 128, 4), 256, 0, stream>>>(o2, outproj_w, outproj_b, op_pad);
    k_conv2<<<dim3(16, 4, 7), 256, 0, stream>>>(op_pad, uw9, unpatch_b, ubuf);
    k_lnpart<<<256, 256, 0, stream>>>(ubuf, acc2);
    k_finalize<<<4, 256, 0, stream>>>(acc2, emb, mod_w, mod_b, mstat);
    k_final<<<1024, 256, 0, stream>>>(ubuf, mstat, enlarge_w, enlarge_b, ff2_w, ff2_b, out);
}